// Round 1
// 218.636 us; speedup vs baseline: 1.0662x; 1.0662x over previous
//
#include <hip/hip_runtime.h>
#include <stdint.h>

#define NN 50000
#define NE 800000
#define NG 64
#define F1 256
#define NBK 196      // dst buckets (d >> 8), 196*256 >= 50000
#define NBS 392      // src buckets (s >> 7), 392*128 >= 50000
#define EPB 2048     // edges per k_bscatter block
#define SCB 391      // ceil(NE / EPB)
#define PB 256       // k_pool2 blocks
#define PCH 196      // nodes per k_pool2 block

typedef __bf16 bf16x8 __attribute__((ext_vector_type(8)));
typedef float f32x4 __attribute__((ext_vector_type(4)));

__device__ __forceinline__ float bf2f(unsigned int u) {
  union { float f; unsigned int i; } v; v.i = (u & 0xffffu) << 16; return v.f;
}
__device__ __forceinline__ unsigned short f2bf(float f) {
  union { float f; unsigned int i; } v; v.f = f;
  unsigned int r = v.i + 0x7fffu + ((v.i >> 16) & 1u);
  return (unsigned short)(r >> 16);
}
__device__ __forceinline__ float asf(unsigned int u) {
  union { unsigned int u; float f; } v; v.u = u; return v.f;
}
__device__ __forceinline__ unsigned int asu(float f) {
  union { float f; unsigned int u; } v; v.f = f; return v.u;
}

// ---- K1: dual coarse histograms (dst>>8 and src>>7), LDS-merged ----
__global__ void k_bhist(const int* __restrict__ ei, int* __restrict__ btot_d,
                        int* __restrict__ btot_s) {
  __shared__ int lhd[NBK];
  __shared__ int lhs[NBS];
  for (int i = threadIdx.x; i < NBK; i += 256) lhd[i] = 0;
  for (int i = threadIdx.x; i < NBS; i += 256) lhs[i] = 0;
  __syncthreads();
  for (int e = blockIdx.x * blockDim.x + threadIdx.x; e < NE; e += gridDim.x * blockDim.x) {
    atomicAdd(&lhs[ei[e] >> 7], 1);
    atomicAdd(&lhd[ei[NE + e] >> 8], 1);
  }
  __syncthreads();
  for (int i = threadIdx.x; i < NBK; i += 256) atomicAdd(&btot_d[i], lhd[i]);
  for (int i = threadIdx.x; i < NBS; i += 256) atomicAdd(&btot_s[i], lhs[i]);
}

// ---- K2: scan both bucket-total arrays -> bases/cursors; rowp[NN]=NE ----
__global__ void k_bscan(const int* __restrict__ btot_d, const int* __restrict__ btot_s,
                        int* __restrict__ bbase, int* __restrict__ bcur,
                        int* __restrict__ sbase, int* __restrict__ scur,
                        int* __restrict__ rowp) {
  __shared__ int buf[512];
  int t = threadIdx.x;
  int v = (t < NBK) ? btot_d[t] : 0;
  buf[t] = v;
  __syncthreads();
  for (int off = 1; off < 512; off <<= 1) {
    int o = (t >= off) ? buf[t - off] : 0;
    __syncthreads();
    buf[t] += o;
    __syncthreads();
  }
  if (t < NBK) { bbase[t] = buf[t] - v; bcur[t] = buf[t] - v; }
  if (t == NBK - 1) bbase[NBK] = buf[t];
  __syncthreads();
  int v2 = (t < NBS) ? btot_s[t] : 0;
  buf[t] = v2;
  __syncthreads();
  for (int off = 1; off < 512; off <<= 1) {
    int o = (t >= off) ? buf[t - off] : 0;
    __syncthreads();
    buf[t] += o;
    __syncthreads();
  }
  if (t < NBS) { sbase[t] = buf[t] - v2; scur[t] = buf[t] - v2; }
  if (t == NBS - 1) sbase[NBS] = buf[t];
  if (t == 0) rowp[NN] = NE;
}

// ---- K3: dual scatter: dst-records {s|d<<16, x[s]} and src-records {d|sl<<16} ----
__global__ __launch_bounds__(256) void k_bscatter(
    const int* __restrict__ ei, const float* __restrict__ x,
    int* __restrict__ bcur, int* __restrict__ scur,
    uint2* __restrict__ recs, unsigned int* __restrict__ srecs) {
  __shared__ int lhd[NBK]; __shared__ int gbd[NBK];
  __shared__ int lhs[NBS]; __shared__ int gbs[NBS];
  int b = blockIdx.x, tid = threadIdx.x;
  int e0 = b * EPB;
  for (int i = tid; i < NBK; i += 256) lhd[i] = 0;
  for (int i = tid; i < NBS; i += 256) lhs[i] = 0;
  __syncthreads();
  unsigned int meta[8]; float xv[8]; int lofd[8]; int bkd[8]; int lofs[8]; int bks[8];
#pragma unroll
  for (int i = 0; i < 8; ++i) {
    int e = e0 + i * 256 + tid;
    bkd[i] = -1;
    if (e < NE) {
      int s = ei[e], d = ei[NE + e];
      bkd[i] = d >> 8; bks[i] = s >> 7;
      meta[i] = (unsigned int)s | ((unsigned int)d << 16);  // s,d < 65536
      xv[i] = x[s];
      lofd[i] = atomicAdd(&lhd[bkd[i]], 1);
      lofs[i] = atomicAdd(&lhs[bks[i]], 1);
    }
  }
  __syncthreads();
  for (int i = tid; i < NBK; i += 256) gbd[i] = atomicAdd(&bcur[i], lhd[i]);
  for (int i = tid; i < NBS; i += 256) gbs[i] = atomicAdd(&scur[i], lhs[i]);
  __syncthreads();
#pragma unroll
  for (int i = 0; i < 8; ++i) {
    if (bkd[i] >= 0) {
      recs[gbd[bkd[i]] + lofd[i]] = make_uint2(meta[i], asu(xv[i]));
      unsigned int s = meta[i] & 0xFFFFu, d = meta[i] >> 16;
      srecs[gbs[bks[i]] + lofs[i]] = d | ((s & 127u) << 16);
    }
  }
}

// ---- K4: per-dst-bucket fine CSR + per-node ax + dg table + colx scatter ----
__global__ __launch_bounds__(256) void k_csr(
    const uint2* __restrict__ recs, const int* __restrict__ bbase,
    const float* __restrict__ x, const int* __restrict__ batch,
    int* __restrict__ rowp, float2* __restrict__ ax,
    int* __restrict__ colx, uint2* __restrict__ dg) {
  __shared__ int cnt[256];
  __shared__ int sc[256];
  __shared__ float xs[256];
  int b = blockIdx.x, tid = threadIdx.x;
  int eb = bbase[b], ee = bbase[b + 1];
  cnt[tid] = 0;
  xs[tid] = 0.0f;
  __syncthreads();
  for (int e = eb + tid; e < ee; e += 256) {
    uint2 r = recs[e];
    int dl = (r.x >> 16) & 255;
    atomicAdd(&cnt[dl], 1);
    atomicAdd(&xs[dl], asf(r.y));
  }
  __syncthreads();
  sc[tid] = cnt[tid];
  __syncthreads();
  for (int off = 1; off < 256; off <<= 1) {
    int o = (tid >= off) ? sc[tid - off] : 0;
    __syncthreads();
    sc[tid] += o;
    __syncthreads();
  }
  int excl = sc[tid] - cnt[tid];
  int i = b * 256 + tid;
  float dinv = 1.0f / fmaxf((float)cnt[tid], 1.0f);
  if (i < NN) {
    rowp[i] = eb + excl;
    ax[i] = make_float2(xs[tid] * dinv, x[i]);
    dg[i] = make_uint2(asu(dinv), (unsigned int)batch[i]);
  }
  __syncthreads();
  sc[tid] = excl;  // cursor
  __syncthreads();
  for (int e = eb + tid; e < ee; e += 256) {
    uint2 r = recs[e];
    int dl = (r.x >> 16) & 255;
    int s = r.x & 0xFFFF;
    int slot = atomicAdd(&sc[dl], 1);
    colx[eb + slot] = s;
  }
}

// ---- K5: per-src-bucket wg rows in LDS (no global atomics), coalesced out ----
__global__ __launch_bounds__(256) void k_csc(
    const unsigned int* __restrict__ srecs, const int* __restrict__ sbase,
    const uint2* __restrict__ dg, float* __restrict__ wg) {
  __shared__ float wgrow[128][64];  // 32KB
  int b = blockIdx.x, tid = threadIdx.x;
  f32x4 zz = {0.f, 0.f, 0.f, 0.f};
  for (int j = tid; j < 2048; j += 256) ((f32x4*)wgrow)[j] = zz;
  __syncthreads();
  int eb = sbase[b], ee = sbase[b + 1];
  for (int e = eb + tid; e < ee; e += 256) {
    unsigned int r = srecs[e];
    int d = r & 0xFFFF;
    int sl = (r >> 16) & 127;
    uint2 t = dg[d];  // {deginv bits, g} — 400KB table, L2-resident
    atomicAdd(&wgrow[sl][t.y], asf(t.x));
  }
  __syncthreads();
  int s0 = b * 128;
  for (int j = tid; j < 2048; j += 256) {
    int row = j >> 4, col = (j & 15) * 4;
    int s = s0 + row;
    if (s < NN) *(f32x4*)&wg[(size_t)s * NG + col] = *(const f32x4*)&wgrow[row][col];
  }
}

// ---- per-graph node count via binary search over sorted batch ----
__global__ void k_cnt(const int* __restrict__ batch, int* __restrict__ cnt) {
  int g = threadIdx.x;
  if (g >= NG) return;
  int lo = 0, hi = NN;
  while (lo < hi) { int m = (lo + hi) >> 1; if (batch[m] < g) lo = m + 1; else hi = m; }
  int a = lo;
  lo = 0; hi = NN;
  while (lo < hi) { int m = (lo + hi) >> 1; if (batch[m] < g + 1) lo = m + 1; else hi = m; }
  cnt[g] = lo - a;
}

// ---- materialize edge-ordered (a0,x): coalesced write, small-table gather ----
__global__ void k_axe(const int* __restrict__ colx, const float2* __restrict__ ax,
                      float2* __restrict__ axe) {
  int e = blockIdx.x * blockDim.x + threadIdx.x;
  if (e >= NE) return;
  axe[e] = ax[colx[e]];
}

// ---- wcat[n][k]: k<256 -> Wl1[k][n], else Wr1[k-256][n] ----
__global__ void k_wprep(const float* __restrict__ Wl1, const float* __restrict__ Wr1,
                        unsigned short* __restrict__ wcat) {
  int t = blockIdx.x * blockDim.x + threadIdx.x;
  if (t >= 256 * 512) return;
  int n = t >> 9, k = t & 511;
  float v = (k < 256) ? Wl1[k * 256 + n] : Wr1[(k - 256) * 256 + n];
  wcat[t] = f2bf(v);
}

// ---- layer-1 mean-aggregation: stream edge-ordered axe, low-rank recompute ----
__global__ __launch_bounds__(256) void k_agg2(
    const float2* __restrict__ axe, const int* __restrict__ rowp,
    const float* __restrict__ Wl0, const float* __restrict__ b0,
    const float* __restrict__ Wr0, unsigned short* __restrict__ aggb) {
  int wid = threadIdx.x >> 6, lane = threadIdx.x & 63;
  int gw = blockIdx.x * 4 + wid;
  int tw = gridDim.x * 4;
  float wl[4], wr[4], bb[4];
#pragma unroll
  for (int k = 0; k < 4; ++k) {
    wl[k] = Wl0[lane * 4 + k];
    wr[k] = Wr0[lane * 4 + k];
    bb[k] = b0[lane * 4 + k];
  }
  for (int d = gw; d < NN; d += tw) {
    int beg = rowp[d], end = rowp[d + 1];
    float a[4] = {0.f, 0.f, 0.f, 0.f};
    float c[4] = {0.f, 0.f, 0.f, 0.f};
    int e = beg;
    for (; e + 3 < end; e += 4) {
      float2 v0 = axe[e], v1 = axe[e + 1], v2 = axe[e + 2], v3 = axe[e + 3];
#pragma unroll
      for (int k = 0; k < 4; ++k) {
        a[k] += fmaxf(fmaf(v0.x, wl[k], fmaf(v0.y, wr[k], bb[k])), 0.0f);
        c[k] += fmaxf(fmaf(v1.x, wl[k], fmaf(v1.y, wr[k], bb[k])), 0.0f);
        a[k] += fmaxf(fmaf(v2.x, wl[k], fmaf(v2.y, wr[k], bb[k])), 0.0f);
        c[k] += fmaxf(fmaf(v3.x, wl[k], fmaf(v3.y, wr[k], bb[k])), 0.0f);
      }
    }
    for (; e < end; ++e) {
      float2 v0 = axe[e];
#pragma unroll
      for (int k = 0; k < 4; ++k)
        a[k] += fmaxf(fmaf(v0.x, wl[k], fmaf(v0.y, wr[k], bb[k])), 0.0f);
    }
    float dinv = 1.0f / fmaxf((float)(end - beg), 1.0f);
    uint2 o;
    o.x = (unsigned int)f2bf((a[0] + c[0]) * dinv) | ((unsigned int)f2bf((a[1] + c[1]) * dinv) << 16);
    o.y = (unsigned int)f2bf((a[2] + c[2]) * dinv) | ((unsigned int)f2bf((a[3] + c[3]) * dinv) << 16);
    *(uint2*)(aggb + (size_t)d * F1 + lane * 4) = o;
  }
}

// ---- layer 1 GEMM: h1 = relu([agg|h0] @ [Wl1;Wr1] + b1), bf16 MFMA ----
// h0 half (kt>=8) is recomputed in-kernel from ax (rank-2) — no h0b buffer.
// BK=32 double-buffer: LDS = 16+16+3 KB -> 3-4 blocks/CU (was 64KB -> 2).
// MFMA operands swapped so C-fragment is transposed: lane holds 4 consecutive
// output columns -> 8B packed stores instead of 64 scalar 2B stores/thread.
#define BM 128
#define BN 128
#define BK 32

__global__ __launch_bounds__(256) void k_gemm1(
    const unsigned short* __restrict__ aggb, const float2* __restrict__ ax,
    const unsigned short* __restrict__ wcat,
    const float* __restrict__ Wl0, const float* __restrict__ b0,
    const float* __restrict__ Wr0, const float* __restrict__ b1,
    unsigned short* __restrict__ h1b) {
  __shared__ unsigned short As[2][BM][BK];
  __shared__ unsigned short Bs[2][BN][BK];
  __shared__ float wl0s[256], wr0s[256], b0s[256];
  int bm = blockIdx.x, ct = blockIdx.y;
  int tid = threadIdx.x;
  int wid = tid >> 6, lane = tid & 63;
  int wr = wid >> 1, wc = wid & 1;
  int rc = lane & 15, kh = lane >> 4;
  int r0 = bm * BM;
  int srow = tid >> 1;   // 0..127: one staged row per thread
  int sslot = tid & 1;   // which 32B half of the 64B k-row

  wl0s[tid] = Wl0[tid];
  wr0s[tid] = Wr0[tid];
  b0s[tid] = b0[tid];

  int rA = r0 + srow;
  bool rAok = rA < NN;
  float2 axv = rAok ? ax[rA] : make_float2(0.f, 0.f);

  f32x4 acc[4][4] = {};  // acc[nf][mf], transposed fragments
  int4 ra0, ra1, rb0, rb1;

#define LOAD_A(kt)                                                             \
  do {                                                                         \
    ra0 = make_int4(0, 0, 0, 0); ra1 = make_int4(0, 0, 0, 0);                  \
    if (rAok) {                                                                \
      const int4* s_ = (const int4*)(aggb + (size_t)rA * F1 + (kt) * BK + sslot * 16); \
      ra0 = s_[0]; ra1 = s_[1];                                                \
    }                                                                          \
  } while (0)

#define LOAD_B(kt)                                                             \
  do {                                                                         \
    const int4* t_ = (const int4*)(wcat + (size_t)(ct * BN + srow) * 512 + (kt) * BK + sslot * 16); \
    rb0 = t_[0]; rb1 = t_[1];                                                  \
  } while (0)

// h0[rA][j] = relu(ax.x*Wl0[j] + ax.y*Wr0[j] + b0[j]) — bit-identical to old k_h0
#define COMP_A(kt)                                                             \
  do {                                                                         \
    int j0_ = ((kt) - 8) * BK + sslot * 16;                                    \
    unsigned int w_[8];                                                        \
    _Pragma("unroll") for (int q = 0; q < 8; ++q) {                            \
      int j_ = j0_ + 2 * q;                                                    \
      float f0_ = fmaxf(fmaf(axv.x, wl0s[j_], fmaf(axv.y, wr0s[j_], b0s[j_])), 0.0f); \
      float f1_ = fmaxf(fmaf(axv.x, wl0s[j_ + 1], fmaf(axv.y, wr0s[j_ + 1], b0s[j_ + 1])), 0.0f); \
      w_[q] = (unsigned int)f2bf(f0_) | ((unsigned int)f2bf(f1_) << 16);       \
    }                                                                          \
    ra0 = make_int4(w_[0], w_[1], w_[2], w_[3]);                               \
    ra1 = make_int4(w_[4], w_[5], w_[6], w_[7]);                               \
  } while (0)

// swizzle: 4 16B slots/row, phys = logical ^ ((row>>1)&3) -> 2-way (free) on read
#define WRITE_AB(buf)                                                          \
  do {                                                                         \
    int sw_ = (srow >> 1) & 3;                                                 \
    int ws0_ = (2 * sslot) ^ sw_;                                              \
    int ws1_ = (2 * sslot + 1) ^ sw_;                                          \
    *(int4*)&As[buf][srow][ws0_ * 8] = ra0;                                    \
    *(int4*)&As[buf][srow][ws1_ * 8] = ra1;                                    \
    *(int4*)&Bs[buf][srow][ws0_ * 8] = rb0;                                    \
    *(int4*)&Bs[buf][srow][ws1_ * 8] = rb1;                                    \
  } while (0)

  LOAD_B(0);
  LOAD_A(0);
  WRITE_AB(0);
  __syncthreads();
  int cur = 0;
  for (int kt = 0; kt < 16; ++kt) {
    if (kt < 15) {
      LOAD_B(kt + 1);
      if (kt + 1 < 8) LOAD_A(kt + 1);
    }
    bf16x8 af[4], bfr[4];
#pragma unroll
    for (int mf = 0; mf < 4; ++mf) {
      int row = wr * 64 + mf * 16 + rc;
      int sl = kh ^ ((row >> 1) & 3);
      af[mf] = *(const bf16x8*)&As[cur][row][sl * 8];
    }
#pragma unroll
    for (int nf = 0; nf < 4; ++nf) {
      int row = wc * 64 + nf * 16 + rc;
      int sl = kh ^ ((row >> 1) & 3);
      bfr[nf] = *(const bf16x8*)&Bs[cur][row][sl * 8];
    }
#pragma unroll
    for (int nf = 0; nf < 4; ++nf)
#pragma unroll
      for (int mf = 0; mf < 4; ++mf)
        acc[nf][mf] = __builtin_amdgcn_mfma_f32_16x16x32_bf16(bfr[nf], af[mf], acc[nf][mf], 0, 0, 0);
    if (kt < 15) {
      if (kt + 1 >= 8) COMP_A(kt + 1);
      WRITE_AB(cur ^ 1);
    }
    __syncthreads();
    cur ^= 1;
  }
#undef LOAD_A
#undef LOAD_B
#undef COMP_A
#undef WRITE_AB

  // transposed epilogue: r from lane&15, 4 consecutive c from (lane>>4)*4+j
#pragma unroll
  for (int nf = 0; nf < 4; ++nf) {
    int c0 = ct * BN + wc * 64 + nf * 16 + kh * 4;
    float4 bb = *(const float4*)(b1 + c0);
#pragma unroll
    for (int mf = 0; mf < 4; ++mf) {
      int r = r0 + wr * 64 + mf * 16 + rc;
      if (r < NN) {
        f32x4 v = acc[nf][mf];
        unsigned int lo = (unsigned int)f2bf(fmaxf(v[0] + bb.x, 0.0f)) |
                          ((unsigned int)f2bf(fmaxf(v[1] + bb.y, 0.0f)) << 16);
        unsigned int hi = (unsigned int)f2bf(fmaxf(v[2] + bb.z, 0.0f)) |
                          ((unsigned int)f2bf(fmaxf(v[3] + bb.w, 0.0f)) << 16);
        *(uint2*)(h1b + (size_t)r * F1 + c0) = make_uint2(lo, hi);
      }
    }
  }
}

// ---- Z-partials as register-tiled fp32 GEMM + fused P segment-sum ----
__global__ __launch_bounds__(512) void k_pool2(
    const unsigned short* __restrict__ h1b, const float* __restrict__ wg,
    const int* __restrict__ batch, float* __restrict__ zpart,
    float* __restrict__ p1) {
  __shared__ float h1s[32][256];
  __shared__ float wgs[32][64];
  int b = blockIdx.x, tid = threadIdx.x;
  int s0 = b * PCH;
  int lim = min(s0 + PCH, NN);
  int gq = tid >> 6;
  int fq = tid & 63;
  int col = tid & 255;
  int half = tid >> 8;
  f32x4 acc[8] = {};
  float pac = 0.0f;
  int curg = -1;
  for (int t0 = 0; t0 < PCH; t0 += 32) {
    int base = s0 + t0;
    {
      int r = tid >> 4;
      int c0 = (tid & 15) * 16;
      int s = base + r;
      uint4 va = make_uint4(0, 0, 0, 0), vb = make_uint4(0, 0, 0, 0);
      if (s < lim) {
        va = *(const uint4*)(h1b + (size_t)s * F1 + c0);
        vb = *(const uint4*)(h1b + (size_t)s * F1 + c0 + 8);
      }
      float* dst = &h1s[r][c0];
      unsigned int u[8] = {va.x, va.y, va.z, va.w, vb.x, vb.y, vb.z, vb.w};
#pragma unroll
      for (int q = 0; q < 8; ++q) {
        dst[2 * q] = bf2f(u[q]);
        union { float f; unsigned int i; } hi; hi.i = u[q] & 0xffff0000u;
        dst[2 * q + 1] = hi.f;
      }
    }
    {
      int r = tid >> 4;
      int c0 = (tid & 15) * 4;
      int s = base + r;
      float4 v = make_float4(0.f, 0.f, 0.f, 0.f);
      if (s < lim) v = *(const float4*)(wg + (size_t)s * NG + c0);
      *(float4*)&wgs[r][c0] = v;
    }
    __syncthreads();
    int rows = min(32, lim - base);
    for (int k = 0; k < rows; ++k) {
      f32x4 hv = *(const f32x4*)&h1s[k][fq << 2];
      f32x4 w0 = *(const f32x4*)&wgs[k][gq << 3];
      f32x4 w1 = *(const f32x4*)&wgs[k][(gq << 3) + 4];
#pragma unroll
      for (int i = 0; i < 4; ++i) acc[i] += w0[i] * hv;
#pragma unroll
      for (int i = 0; i < 4; ++i) acc[4 + i] += w1[i] * hv;
    }
    int kend = min(half * 16 + 16, rows);
    for (int k = half * 16; k < kend; ++k) {
      int g = batch[base + k];
      if (g != curg) {
        if (curg >= 0) atomicAdd(&p1[curg * F1 + col], pac);
        pac = 0.0f;
        curg = g;
      }
      pac += h1s[k][col];
    }
    __syncthreads();
  }
  if (curg >= 0) atomicAdd(&p1[curg * F1 + col], pac);
  float* zp = zpart + ((size_t)b * 64 + gq * 8) * F1 + (fq << 2);
#pragma unroll
  for (int i = 0; i < 8; ++i) *(f32x4*)(zp + (size_t)i * F1) = acc[i];
}

// ---- parallel zpart reduction: grid (NG, 4), atomic merge into zeroed z ----
__global__ void k_zred(const float* __restrict__ zpart, float* __restrict__ z) {
  int g = blockIdx.x, q = blockIdx.y, t = threadIdx.x;
  float a = 0.0f;
  for (int b = q * 64; b < q * 64 + 64; ++b)
    a += zpart[((size_t)b * 64 + g) * F1 + t];
  atomicAdd(&z[g * F1 + t], a);
}

// ---- final: g = (Z/cnt)@Wl2 + b2 + (P/cnt)@Wr2, then LayerNorm ----
__global__ void k_final(const float* __restrict__ z, const float* __restrict__ p1,
                        const int* __restrict__ cnt,
                        const float* __restrict__ Wl2, const float* __restrict__ b2,
                        const float* __restrict__ Wr2, const float* __restrict__ gamma,
                        const float* __restrict__ beta, float* __restrict__ out) {
  __shared__ float s1[128], s2[128];
  int g = blockIdx.x, j = threadIdx.x;
  float invc = 1.0f / fmaxf((float)cnt[g], 1.0f);
  float acc = 0.0f;
  for (int k = 0; k < 256; ++k) {
    acc += z[g * 256 + k] * Wl2[k * 128 + j] + p1[g * 256 + k] * Wr2[k * 128 + j];
  }
  acc = acc * invc + b2[j];
  s1[j] = acc; s2[j] = acc * acc;
  __syncthreads();
  for (int off = 64; off > 0; off >>= 1) {
    if (j < off) { s1[j] += s1[j + off]; s2[j] += s2[j + off]; }
    __syncthreads();
  }
  float mu = s1[0] / 128.0f;
  float var = s2[0] / 128.0f - mu * mu;
  out[g * 128 + j] = (acc - mu) * rsqrtf(var + 1e-5f) * gamma[j] + beta[j];
}

extern "C" void kernel_launch(void* const* d_in, const int* in_sizes, int n_in,
                              void* d_out, int out_size, void* d_ws, size_t ws_size,
                              hipStream_t stream) {
  const float* x = (const float*)d_in[0];
  const int* ei = (const int*)d_in[1];
  const int* batch = (const int*)d_in[2];
  const float* Wl0 = (const float*)d_in[3];
  const float* b0 = (const float*)d_in[4];
  const float* Wr0 = (const float*)d_in[5];
  const float* Wl1 = (const float*)d_in[6];
  const float* b1 = (const float*)d_in[7];
  const float* Wr1 = (const float*)d_in[8];
  const float* Wl2 = (const float*)d_in[9];
  const float* b2 = (const float*)d_in[10];
  const float* Wr2 = (const float*)d_in[11];
  const float* gamma = (const float*)d_in[12];
  const float* beta = (const float*)d_in[13];
  float* out = (float*)d_out;

  char* p = (char*)d_ws;
  auto alloc = [&](size_t bytes) {
    char* r = p;
    p += (bytes + 511) & ~(size_t)511;
    return r;
  };
  unsigned short* h1b = (unsigned short*)alloc((size_t)NN * F1 * 2);
  unsigned short* aggb = (unsigned short*)alloc((size_t)NN * F1 * 2);  // hosts recs+srecs+colx (early), zpart (late)
  float2* axe = (float2*)alloc((size_t)NE * 8);
  int* rowp = (int*)alloc((size_t)(NN + 1) * 4);
  float2* ax = (float2*)alloc((size_t)NN * 8);
  uint2* dg = (uint2*)alloc((size_t)NN * 8);
  int* cnt = (int*)alloc((size_t)NG * 4);
  float* z = (float*)alloc((size_t)NG * F1 * 4);
  float* p1 = (float*)alloc((size_t)NG * F1 * 4);
  unsigned short* wcat = (unsigned short*)alloc((size_t)256 * 512 * 2);
  int* btot_d = (int*)alloc((size_t)NBK * 4);
  int* btot_s = (int*)alloc((size_t)NBS * 4);
  int* bbase = (int*)alloc((size_t)(NBK + 1) * 4);
  int* bcur = (int*)alloc((size_t)NBK * 4);
  int* sbase = (int*)alloc((size_t)(NBS + 1) * 4);
  int* scur = (int*)alloc((size_t)NBS * 4);
  float* wg = (float*)alloc((size_t)NN * NG * 4);
  // Aliasing inside aggb (25.6MB): recs (uint2, 6.4MB @0), srecs (uint, 3.2MB
  // @6.4MB), colx (int, 3.2MB @9.6MB). recs dead after k_csr; srecs dead after
  // k_csc; colx dead after k_axe — all complete before k_agg2 writes aggb.
  // zpart (16.8MB) aliases aggb after k_gemm1 completes. Stream-ordered.
  uint2* recs = (uint2*)aggb;
  unsigned int* srecs = (unsigned int*)(aggb + (size_t)NE * 4);
  int* colx = (int*)(aggb + (size_t)NE * 6);
  float* zpart = (float*)aggb;

  hipMemsetAsync(btot_d, 0, (size_t)NBK * 4, stream);
  hipMemsetAsync(btot_s, 0, (size_t)NBS * 4, stream);
  hipMemsetAsync(p1, 0, (size_t)NG * F1 * 4, stream);
  hipMemsetAsync(z, 0, (size_t)NG * F1 * 4, stream);

  k_bhist<<<256, 256, 0, stream>>>(ei, btot_d, btot_s);
  k_bscan<<<1, 512, 0, stream>>>(btot_d, btot_s, bbase, bcur, sbase, scur, rowp);
  k_bscatter<<<SCB, 256, 0, stream>>>(ei, x, bcur, scur, recs, srecs);
  k_csr<<<NBK, 256, 0, stream>>>(recs, bbase, x, batch, rowp, ax, colx, dg);
  k_csc<<<NBS, 256, 0, stream>>>(srecs, sbase, dg, wg);
  k_cnt<<<1, 64, 0, stream>>>(batch, cnt);
  k_axe<<<(NE + 255) / 256, 256, 0, stream>>>(colx, ax, axe);
  k_wprep<<<(256 * 512 + 255) / 256, 256, 0, stream>>>(Wl1, Wr1, wcat);
  k_agg2<<<2048, 256, 0, stream>>>(axe, rowp, Wl0, b0, Wr0, aggb);
  dim3 gg(391, 2);
  k_gemm1<<<gg, 256, 0, stream>>>(aggb, ax, wcat, Wl0, b0, Wr0, b1, h1b);
  k_pool2<<<PB, 512, 0, stream>>>(h1b, wg, batch, zpart, p1);
  dim3 zg(NG, 4);
  k_zred<<<zg, 256, 0, stream>>>(zpart, z);
  k_final<<<NG, 128, 0, stream>>>(z, p1, cnt, Wl2, b2, Wr2, gamma, beta, out);
}